// Round 4
// baseline (447.220 us; speedup 1.0000x reference)
//
#include <hip/hip_runtime.h>
#include <cstdint>
#include <cstddef>

// Problem constants
#define NTOK 2048      // B*S
#define DDIM 1024
#define FDIM 2048
#define NEXP 14
#define MAXT 2048
#define BM   160       // m-tile rows: ceil(~293/160)=2 m-tiles/expert

typedef __attribute__((ext_vector_type(8))) short short8;
typedef __attribute__((ext_vector_type(4))) float floatx4;

__device__ __forceinline__ unsigned pack2bf(float lo, float hi) {
    unsigned a = __float_as_uint(lo), b = __float_as_uint(hi);
    return ((a + 0x8000u) >> 16) | ((b + 0x8000u) & 0xffff0000u);
}
__device__ __forceinline__ unsigned short f2bf1(float f) {
    return (unsigned short)((__float_as_uint(f) + 0x8000u) >> 16);
}

// async global->LDS, 16B per lane; lds base must be wave-uniform
__device__ __forceinline__ void glds16(const void* g, void* lds) {
    __builtin_amdgcn_global_load_lds((const __attribute__((address_space(1))) unsigned*)g,
                                     (__attribute__((address_space(3))) unsigned*)lds, 16, 0, 0);
}

// B LDS chunk swizzle: write groups (n stride 4) and read groups (n stride 1)
// both hit 8 distinct 16B bank-quads.
__device__ __forceinline__ int bswz(int n) { return ((n >> 2) ^ n ^ (n >> 4)) & 7; }

#define SBAR() __builtin_amdgcn_sched_barrier(0)

// ---------------- convert x -> bf16, zero counters + out0/out1 ----------------
__global__ __launch_bounds__(256) void cvtx_kernel(const float* __restrict__ x,
                                                   unsigned short* __restrict__ xb,
                                                   int* __restrict__ cnt,
                                                   float* __restrict__ out0z,
                                                   float* __restrict__ o1z) {
    if (blockIdx.x == 0 && threadIdx.x < NEXP) cnt[threadIdx.x] = 0;
    const size_t tid = (size_t)blockIdx.x * 256 + threadIdx.x;
    const size_t i = tid * 8;
    float4 a = *(const float4*)(x + i);
    float4 b = *(const float4*)(x + i + 4);
    uint4 u;
    u.x = pack2bf(a.x, a.y); u.y = pack2bf(a.z, a.w);
    u.z = pack2bf(b.x, b.y); u.w = pack2bf(b.z, b.w);
    *(uint4*)(xb + i) = u;
    // zero the split-K accumulation targets (8 floats each)
    float4 z = {0.f, 0.f, 0.f, 0.f};
    *(float4*)(out0z + i) = z; *(float4*)(out0z + i + 4) = z;
    *(float4*)(o1z + i) = z;   *(float4*)(o1z + i + 4) = z;
}

// ---------------- gating: one wave per token ----------------
__global__ __launch_bounds__(256) void gate_kernel(
    const float* __restrict__ x, const float* __restrict__ gw,
    int* __restrict__ cnt, int* __restrict__ lists, float* __restrict__ wt)
{
    const int wave = threadIdx.x >> 6, lane = threadIdx.x & 63;
    const int n = blockIdx.x * 4 + wave;
    float part[NEXP];
#pragma unroll
    for (int e = 0; e < NEXP; ++e) part[e] = 0.f;
    const float4* xr = (const float4*)(x + (size_t)n * DDIM);
#pragma unroll
    for (int kk = 0; kk < 4; ++kk) {
        const float4 xv = xr[kk * 64 + lane];
#pragma unroll
        for (int e = 0; e < NEXP; ++e) {
            const float4 g = ((const float4*)(gw + e * DDIM))[kk * 64 + lane];
            part[e] = fmaf(xv.x, g.x, fmaf(xv.y, g.y, fmaf(xv.z, g.z, fmaf(xv.w, g.w, part[e]))));
        }
    }
#pragma unroll
    for (int e = 0; e < NEXP; ++e) {
        float v = part[e];
        for (int off = 32; off; off >>= 1) v += __shfl_xor(v, off);
        part[e] = v;
    }
    int i0 = 0; float l0 = part[0];
#pragma unroll
    for (int e = 1; e < NEXP; ++e) if (part[e] > l0) { l0 = part[e]; i0 = e; }
    int i1 = -1; float l1 = -3.0e38f;
#pragma unroll
    for (int e = 0; e < NEXP; ++e) if (e != i0 && part[e] > l1) { l1 = part[e]; i1 = e; }
    if (lane == 0) {
        const float r  = __expf(l1 - l0);
        wt[2 * n]     = 1.f / (1.f + r);
        wt[2 * n + 1] = r / (1.f + r);
        int p0 = atomicAdd(&cnt[i0], 1); lists[i0 * MAXT + p0] = 2 * n;
        int p1 = atomicAdd(&cnt[i1], 1); lists[i1 * MAXT + p1] = 2 * n + 1;
    }
}

// ---------------- build compact (expert, m-tile) job list ----------------
#define MAXJOBS 40
__global__ void jobs_kernel(const int* __restrict__ cnt, int* __restrict__ job_e,
                            int* __restrict__ job_mt, int* __restrict__ njobs) {
    if (threadIdx.x == 0) {
        int J = 0;
        for (int e = 0; e < NEXP; ++e) {
            const int m = (cnt[e] + BM - 1) / BM;
            for (int i = 0; i < m; ++i) { job_e[J] = e; job_mt[J] = i; ++J; }
        }
        njobs[0] = J;
    }
}

// ======== shared GEMM-core macros (depth-3 B rotation, counted vmcnt) ========
// R_j holds B-tile t with t%3==j. At step i: WRITEB(R_{(i+1)%3}) -> LDS[(i+1)&1],
// LOADB(R_{i%3}, tile i+3). End-of-step s_waitcnt vmcnt(8) drains A(i+1) glds16
// and B(i+2) (aged >= 1.4 steps); B(i+3) stays in flight across the barrier.
#define LOADB(dst, kbase, STRIDE) {                                           \
    _Pragma("unroll") for (int jj = 0; jj < 8; ++jj)                          \
        dst[jj] = *(const floatx4*)(bG + (size_t)((kbase) + kg * 8 + jj) * (STRIDE)); }

#define WRITEB(src, buf) {                                                    \
    _Pragma("unroll") for (int nn = 0; nn < 4; ++nn) {                        \
        const int n_ = n4 + nn, slot_ = kg ^ bswz(n_);                        \
        uint4 u_;                                                             \
        u_.x = pack2bf(src[0][nn], src[1][nn]); u_.y = pack2bf(src[2][nn], src[3][nn]); \
        u_.z = pack2bf(src[4][nn], src[5][nn]); u_.w = pack2bf(src[6][nn], src[7][nn]); \
        *(uint4*)&Bs[buf][n_ * 64 + slot_ * 8] = u_; } }

#define STAGEA(buf, koff) {                                                   \
    _Pragma("unroll") for (int q = 0; q < 5; ++q)                             \
        glds16(aGp[q] + (koff), &As[buf][(wave * 40 + q * 8) * 64]); }

#define COMPUTE(buf) {                                                        \
    _Pragma("unroll") for (int ks = 0; ks < 2; ++ks) {                        \
        const int c_ = ks * 4 + lq;                                           \
        short8 af[5], bf[4];                                                  \
        _Pragma("unroll") for (int ii = 0; ii < 5; ++ii) {                    \
            const int r_ = wm + ii * 16 + lrow;                               \
            af[ii] = *(const short8*)&As[buf][r_ * 64 + ((c_ ^ (r_ & 7)) * 8)]; } \
        _Pragma("unroll") for (int jn = 0; jn < 4; ++jn) {                    \
            const int n_ = wn + jn * 16 + lrow;                               \
            bf[jn] = *(const short8*)&Bs[buf][n_ * 64 + ((c_ ^ bswz(n_)) * 8)]; } \
        __builtin_amdgcn_s_setprio(1);                                        \
        _Pragma("unroll") for (int ii = 0; ii < 5; ++ii)                      \
            _Pragma("unroll") for (int jn = 0; jn < 4; ++jn)                  \
                acc[ii][jn] = __builtin_amdgcn_mfma_f32_16x16x32_bf16(af[ii], bf[jn], acc[ii][jn], 0, 0, 0); \
        __builtin_amdgcn_s_setprio(0); } }

#define STEP_FULL(i, Rw, Rl, STRIDE) {                                        \
    STAGEA(((i) + 1) & 1, ((i) + 1) * 64);                                    \
    WRITEB(Rw, ((i) + 1) & 1);                                                \
    SBAR();                                                                   \
    LOADB(Rl, ((i) + 3) * 64, STRIDE);                                        \
    SBAR();                                                                   \
    COMPUTE((i) & 1);                                                         \
    asm volatile("s_waitcnt vmcnt(8) lgkmcnt(0)" ::: "memory");               \
    __builtin_amdgcn_s_barrier(); }

#define STEP_NOLOAD(i, Rw) {                                                  \
    STAGEA(((i) + 1) & 1, ((i) + 1) * 64);                                    \
    WRITEB(Rw, ((i) + 1) & 1);                                                \
    SBAR();                                                                   \
    COMPUTE((i) & 1);                                                         \
    asm volatile("s_waitcnt vmcnt(0) lgkmcnt(0)" ::: "memory");               \
    __builtin_amdgcn_s_barrier(); }

// prologue: R0=tile0 (oldest, drained by pack), A(0), pack tile0, R1, R2;
// vmcnt(16) drains A(0); R1/R2 stay in flight.
#define GEMM_PROLOGUE(STRIDE) {                                               \
    LOADB(brv0, 0, STRIDE);                                                   \
    STAGEA(0, 0);                                                             \
    WRITEB(brv0, 0);                                                          \
    SBAR();                                                                   \
    LOADB(brv1, 64, STRIDE);                                                  \
    LOADB(brv2, 128, STRIDE);                                                 \
    SBAR();                                                                   \
    asm volatile("s_waitcnt vmcnt(16) lgkmcnt(0)" ::: "memory");              \
    __builtin_amdgcn_s_barrier(); }

// 16 K-steps total: 4 x 3 steady + step12 + 2 noload + final compute
#define GEMM_MAINLOOP(STRIDE) {                                               \
    _Pragma("unroll 1")                                                       \
    for (int g = 0; g < 4; ++g) {                                             \
        const int i = g * 3;                                                  \
        STEP_FULL(i,     brv1, brv0, STRIDE);                                 \
        STEP_FULL(i + 1, brv2, brv1, STRIDE);                                 \
        STEP_FULL(i + 2, brv0, brv2, STRIDE);                                 \
    }                                                                         \
    STEP_FULL(12, brv1, brv0, STRIDE);                                        \
    STEP_NOLOAD(13, brv2);                                                    \
    STEP_NOLOAD(14, brv0);                                                    \
    COMPUTE(1); }

// ---------------- GEMM1: hh[p][F] = gelu(xb[tok] @ w1[e] + b1[e]) ----------------
// BM=160, BN=128, BK=64, NK=16.
__global__ __launch_bounds__(256, 2) void gemm1_kernel(
    const unsigned short* __restrict__ xb, const float* __restrict__ w1,
    const float* __restrict__ b1, const int* __restrict__ cnt,
    const int* __restrict__ lists, const int* __restrict__ job_e,
    const int* __restrict__ job_mt, const int* __restrict__ njobs,
    unsigned short* __restrict__ hh)
{
    const int j = blockIdx.y;
    if (j >= njobs[0]) return;
    const int e = job_e[j], mt = job_mt[j], nt = blockIdx.x;
    const int count = cnt[e];
    const int* list = lists + e * MAXT + mt * BM;
    const int mloc = min(BM, count - mt * BM);

    __shared__ __align__(16) unsigned short As[2][BM * 64];    // 40 KB
    __shared__ __align__(16) unsigned short Bs[2][128 * 64];   // 32 KB

    const int t = threadIdx.x, lane = t & 63, wave = t >> 6;
    const int lrow = lane & 15, lq = lane >> 4;
    const int wm = (wave & 1) * 80, wn = (wave >> 1) * 64;

    const int achk = (lane & 7) ^ (lane >> 3);
    const unsigned short* aGp[5];
#pragma unroll
    for (int q = 0; q < 5; ++q) {
        const int r = wave * 40 + q * 8 + (lane >> 3);
        aGp[q] = xb + (size_t)(list[min(r, mloc - 1)] >> 1) * DDIM + achk * 8;
    }

    const int n4 = (t & 31) * 4, kg = t >> 5;
    const float* bG = w1 + (size_t)e * DDIM * FDIM + nt * 128 + n4;

    floatx4 acc[5][4];
#pragma unroll
    for (int ii = 0; ii < 5; ++ii)
#pragma unroll
        for (int jn = 0; jn < 4; ++jn) acc[ii][jn] = (floatx4)0.f;

    floatx4 brv0[8], brv1[8], brv2[8];

    GEMM_PROLOGUE(FDIM);
    GEMM_MAINLOOP(FDIM);

    // epilogue: bias + exact gelu -> hh (bf16)
#pragma unroll
    for (int jn = 0; jn < 4; ++jn) {
        const int n = nt * 128 + wn + jn * 16 + lrow;
        const float bias = b1[e * FDIM + n];
#pragma unroll
        for (int ii = 0; ii < 5; ++ii) {
#pragma unroll
            for (int r = 0; r < 4; ++r) {
                const int m = wm + ii * 16 + lq * 4 + r;
                if (m < mloc) {
                    const int pp = list[m];
                    float v = acc[ii][jn][r] + bias;
                    v = 0.5f * v * (1.0f + erff(v * 0.70710678118654752f));
                    hh[(size_t)pp * FDIM + n] = f2bf1(v);
                }
            }
        }
    }
}

// ---------------- GEMM2: out_slot[tok][D] += wt[p]*(hh[p] @ w2[e] [+ b2[e]]) ----------------
// BM=160, BN=128, BK=64, split-K=2 (blockIdx.z), NK=16 per half; atomic f32 adds.
__global__ __launch_bounds__(256, 2) void gemm2_kernel(
    const unsigned short* __restrict__ hh, const float* __restrict__ w2,
    const float* __restrict__ b2, const int* __restrict__ cnt,
    const int* __restrict__ lists, const int* __restrict__ job_e,
    const int* __restrict__ job_mt, const int* __restrict__ njobs,
    const float* __restrict__ wt, float* __restrict__ out0, float* __restrict__ out1)
{
    const int j = blockIdx.y;
    if (j >= njobs[0]) return;
    const int e = job_e[j], mt = job_mt[j], nt = blockIdx.x, sk = blockIdx.z;
    const int count = cnt[e];
    const int* list = lists + e * MAXT + mt * BM;
    const int mloc = min(BM, count - mt * BM);

    __shared__ __align__(16) unsigned short As[2][BM * 64];    // 40 KB
    __shared__ __align__(16) unsigned short Bs[2][128 * 64];   // 32 KB

    const int t = threadIdx.x, lane = t & 63, wave = t >> 6;
    const int lrow = lane & 15, lq = lane >> 4;
    const int wm = (wave & 1) * 80, wn = (wave >> 1) * 64;

    const int achk = (lane & 7) ^ (lane >> 3);
    const unsigned short* aGp[5];
#pragma unroll
    for (int q = 0; q < 5; ++q) {
        const int r = wave * 40 + q * 8 + (lane >> 3);
        aGp[q] = hh + (size_t)list[min(r, mloc - 1)] * FDIM + sk * 1024 + achk * 8;
    }

    const int n4 = (t & 31) * 4, kg = t >> 5;
    const float* bG = w2 + (size_t)e * FDIM * DDIM + (size_t)sk * 1024 * DDIM + nt * 128 + n4;

    floatx4 acc[5][4];
#pragma unroll
    for (int ii = 0; ii < 5; ++ii)
#pragma unroll
        for (int jn = 0; jn < 4; ++jn) acc[ii][jn] = (floatx4)0.f;

    floatx4 brv0[8], brv1[8], brv2[8];

    GEMM_PROLOGUE(DDIM);
    GEMM_MAINLOOP(DDIM);

#pragma unroll
    for (int jn = 0; jn < 4; ++jn) {
        const int n = nt * 128 + wn + jn * 16 + lrow;
        const float bias = (sk == 0) ? b2[e * DDIM + n] : 0.f;
#pragma unroll
        for (int ii = 0; ii < 5; ++ii) {
#pragma unroll
            for (int r = 0; r < 4; ++r) {
                const int m = wm + ii * 16 + lq * 4 + r;
                if (m < mloc) {
                    const int pp = list[m];
                    const int tok = pp >> 1;
                    const float v = (acc[ii][jn][r] + bias) * wt[pp];
                    float* dst = (pp & 1) ? out1 : out0;
                    atomicAdd(dst + (size_t)tok * DDIM + n, v);
                }
            }
        }
    }
}

// ---------------- finalize: out = clip(x + out0 + out1) ----------------
__global__ __launch_bounds__(256) void finalize_kernel(
    const float* __restrict__ x, const float* __restrict__ o1,
    float* __restrict__ out)   // out currently holds out0
{
    const size_t i = ((size_t)blockIdx.x * 256 + threadIdx.x) * 4;
    float4 xv = *(const float4*)(x + i);
    float4 a  = *(const float4*)(out + i);
    float4 b  = *(const float4*)(o1 + i);
    float4 r;
    r.x = fminf(fmaxf(xv.x + a.x + b.x, -100.f), 100.f);
    r.y = fminf(fmaxf(xv.y + a.y + b.y, -100.f), 100.f);
    r.z = fminf(fmaxf(xv.z + a.z + b.z, -100.f), 100.f);
    r.w = fminf(fmaxf(xv.w + a.w + b.w, -100.f), 100.f);
    *(float4*)(out + i) = r;
}

extern "C" void kernel_launch(void* const* d_in, const int* in_sizes, int n_in,
                              void* d_out, int out_size, void* d_ws, size_t ws_size,
                              hipStream_t stream) {
    const float* h  = (const float*)d_in[0];
    const float* gw = (const float*)d_in[1];
    const float* w1 = (const float*)d_in[2];
    const float* b1 = (const float*)d_in[3];
    const float* w2 = (const float*)d_in[4];
    const float* b2 = (const float*)d_in[5];
    float* out = (float*)d_out;

    // workspace layout (bytes)
    char* ws = (char*)d_ws;
    int*   cnt    = (int*)ws;                         // 256
    int*   lists  = (int*)(ws + 256);                 // 114688
    float* wt     = (float*)(ws + 114944);            // 16384 -> 131328
    int*   job_e  = (int*)(ws + 131328);              // 512
    int*   job_mt = (int*)(ws + 131840);              // 512
    int*   njobs  = (int*)(ws + 132352);              // 256 -> 132608
    unsigned short* xb = (unsigned short*)(ws + 262144);            // 4 MB
    float* o1     = (float*)(ws + 262144 + 4194304);                // 8 MB
    unsigned short* hhb = (unsigned short*)(ws + 262144 + 4194304 + 8388608); // 16 MB
    // total ~28.3 MB

    cvtx_kernel<<<NTOK * DDIM / (256 * 8), 256, 0, stream>>>(h, xb, cnt, out, o1);
    gate_kernel<<<NTOK / 4, 256, 0, stream>>>(h, gw, cnt, lists, wt);
    jobs_kernel<<<1, 64, 0, stream>>>(cnt, job_e, job_mt, njobs);
    gemm1_kernel<<<dim3(FDIM / 128, MAXJOBS), 256, 0, stream>>>(xb, w1, b1, cnt, lists, job_e, job_mt, njobs, hhb);
    gemm2_kernel<<<dim3(DDIM / 128, MAXJOBS, 2), 256, 0, stream>>>(hhb, w2, b2, cnt, lists, job_e, job_mt, njobs, wt, out, o1);
    finalize_kernel<<<NTOK * DDIM / (256 * 4), 256, 0, stream>>>(h, o1, out);
}

// Round 5
// 419.154 us; speedup vs baseline: 1.0670x; 1.0670x over previous
//
#include <hip/hip_runtime.h>
#include <cstdint>
#include <cstddef>

// Problem constants
#define NTOK 2048      // B*S
#define DDIM 1024
#define FDIM 2048
#define NEXP 14
#define MAXT 2048
#define BM   160       // m-tile rows: ceil(~293/160)=2 m-tiles/expert

typedef __attribute__((ext_vector_type(8))) short short8;
typedef __attribute__((ext_vector_type(4))) float floatx4;

__device__ __forceinline__ unsigned pack2bf(float lo, float hi) {
    unsigned a = __float_as_uint(lo), b = __float_as_uint(hi);
    return ((a + 0x8000u) >> 16) | ((b + 0x8000u) & 0xffff0000u);
}
__device__ __forceinline__ unsigned short f2bf1(float f) {
    return (unsigned short)((__float_as_uint(f) + 0x8000u) >> 16);
}

// async global->LDS, 16B per lane; lds base must be wave-uniform
__device__ __forceinline__ void glds16(const void* g, void* lds) {
    __builtin_amdgcn_global_load_lds((const __attribute__((address_space(1))) unsigned*)g,
                                     (__attribute__((address_space(3))) unsigned*)lds, 16, 0, 0);
}

// B LDS chunk swizzle: write groups (n stride 4) and read groups (n stride 1)
// both hit 8 distinct 16B bank-quads.
__device__ __forceinline__ int bswz(int n) { return ((n >> 2) ^ n ^ (n >> 4)) & 7; }

#define SBAR() __builtin_amdgcn_sched_barrier(0)

// ---------------- convert x -> bf16, zero counters ----------------
__global__ __launch_bounds__(256) void cvtx_kernel(const float* __restrict__ x,
                                                   unsigned short* __restrict__ xb,
                                                   int* __restrict__ cnt) {
    if (blockIdx.x == 0 && threadIdx.x < NEXP) cnt[threadIdx.x] = 0;
    const size_t i = ((size_t)blockIdx.x * 256 + threadIdx.x) * 8;
    float4 a = *(const float4*)(x + i);
    float4 b = *(const float4*)(x + i + 4);
    uint4 u;
    u.x = pack2bf(a.x, a.y); u.y = pack2bf(a.z, a.w);
    u.z = pack2bf(b.x, b.y); u.w = pack2bf(b.z, b.w);
    *(uint4*)(xb + i) = u;
}

// ---------------- gating: one wave per token ----------------
__global__ __launch_bounds__(256) void gate_kernel(
    const float* __restrict__ x, const float* __restrict__ gw,
    int* __restrict__ cnt, int* __restrict__ lists, float* __restrict__ wt)
{
    const int wave = threadIdx.x >> 6, lane = threadIdx.x & 63;
    const int n = blockIdx.x * 4 + wave;
    float part[NEXP];
#pragma unroll
    for (int e = 0; e < NEXP; ++e) part[e] = 0.f;
    const float4* xr = (const float4*)(x + (size_t)n * DDIM);
#pragma unroll
    for (int kk = 0; kk < 4; ++kk) {
        const float4 xv = xr[kk * 64 + lane];
#pragma unroll
        for (int e = 0; e < NEXP; ++e) {
            const float4 g = ((const float4*)(gw + e * DDIM))[kk * 64 + lane];
            part[e] = fmaf(xv.x, g.x, fmaf(xv.y, g.y, fmaf(xv.z, g.z, fmaf(xv.w, g.w, part[e]))));
        }
    }
#pragma unroll
    for (int e = 0; e < NEXP; ++e) {
        float v = part[e];
        for (int off = 32; off; off >>= 1) v += __shfl_xor(v, off);
        part[e] = v;
    }
    int i0 = 0; float l0 = part[0];
#pragma unroll
    for (int e = 1; e < NEXP; ++e) if (part[e] > l0) { l0 = part[e]; i0 = e; }
    int i1 = -1; float l1 = -3.0e38f;
#pragma unroll
    for (int e = 0; e < NEXP; ++e) if (e != i0 && part[e] > l1) { l1 = part[e]; i1 = e; }
    if (lane == 0) {
        const float r  = __expf(l1 - l0);
        wt[2 * n]     = 1.f / (1.f + r);
        wt[2 * n + 1] = r / (1.f + r);
        int p0 = atomicAdd(&cnt[i0], 1); lists[i0 * MAXT + p0] = 2 * n;
        int p1 = atomicAdd(&cnt[i1], 1); lists[i1 * MAXT + p1] = 2 * n + 1;
    }
}

// ---------------- build compact (expert, m-tile) job list ----------------
#define MAXJOBS 40
__global__ void jobs_kernel(const int* __restrict__ cnt, int* __restrict__ job_e,
                            int* __restrict__ job_mt, int* __restrict__ njobs) {
    if (threadIdx.x == 0) {
        int J = 0;
        for (int e = 0; e < NEXP; ++e) {
            const int m = (cnt[e] + BM - 1) / BM;
            for (int i = 0; i < m; ++i) { job_e[J] = e; job_mt[J] = i; ++J; }
        }
        njobs[0] = J;
    }
}

// ======== shared GEMM-core macros (counted-vmcnt pipelined schedule) ========
// Invariant at top of steady iteration i: LDS[i&1] holds tile i (barrier
// passed), brv_cur holds raw f32 B(i+1). Schedule per step:
//   glds16 A(i+1) x5 ; pack+ds_write B(i+1)->LDS[(i+1)&1]
//   load B(i+2)->brv_nxt [8 vmem, newest]
//   ds_read + MFMA tile i
//   s_waitcnt vmcnt(8) lgkmcnt(0)   <- drains the 5 glds16 + ds_writes ONLY;
//   s_barrier                          B(i+2) stays in flight across barrier
#define LOADB(dst, kbase, STRIDE) {                                           \
    _Pragma("unroll") for (int jj = 0; jj < 8; ++jj)                          \
        dst[jj] = *(const floatx4*)(bG + (size_t)((kbase) + kg * 8 + jj) * (STRIDE)); }

#define WRITEB(src, buf) {                                                    \
    _Pragma("unroll") for (int nn = 0; nn < 4; ++nn) {                        \
        const int n_ = n4 + nn, slot_ = kg ^ bswz(n_);                        \
        uint4 u_;                                                             \
        u_.x = pack2bf(src[0][nn], src[1][nn]); u_.y = pack2bf(src[2][nn], src[3][nn]); \
        u_.z = pack2bf(src[4][nn], src[5][nn]); u_.w = pack2bf(src[6][nn], src[7][nn]); \
        *(uint4*)&Bs[buf][n_ * 64 + slot_ * 8] = u_; } }

// wave stages rows wave*40 .. wave*40+39 (5 x 8-row glds16); 40 % 8 == 0 so
// the (row&7) XOR-swizzle stays consistent with the per-lane source chunk.
#define STAGEA(buf, koff) {                                                   \
    _Pragma("unroll") for (int q = 0; q < 5; ++q)                             \
        glds16(aGp[q] + (koff), &As[buf][(wave * 40 + q * 8) * 64]); }

#define COMPUTE(buf) {                                                        \
    _Pragma("unroll") for (int ks = 0; ks < 2; ++ks) {                        \
        const int c_ = ks * 4 + lq;                                           \
        short8 af[5], bf[4];                                                  \
        _Pragma("unroll") for (int ii = 0; ii < 5; ++ii) {                    \
            const int r_ = wm + ii * 16 + lrow;                               \
            af[ii] = *(const short8*)&As[buf][r_ * 64 + ((c_ ^ (r_ & 7)) * 8)]; } \
        _Pragma("unroll") for (int jn = 0; jn < 4; ++jn) {                    \
            const int n_ = wn + jn * 16 + lrow;                               \
            bf[jn] = *(const short8*)&Bs[buf][n_ * 64 + ((c_ ^ bswz(n_)) * 8)]; } \
        __builtin_amdgcn_s_setprio(1);                                        \
        _Pragma("unroll") for (int ii = 0; ii < 5; ++ii)                      \
            _Pragma("unroll") for (int jn = 0; jn < 4; ++jn)                  \
                acc[ii][jn] = __builtin_amdgcn_mfma_f32_16x16x32_bf16(af[ii], bf[jn], acc[ii][jn], 0, 0, 0); \
        __builtin_amdgcn_s_setprio(0); } }

#define STEADY(i, curbuf, brv_c, brv_n, STRIDE) {                             \
    STAGEA((curbuf) ^ 1, ((i) + 1) * 64);                                     \
    WRITEB(brv_c, (curbuf) ^ 1);                                              \
    SBAR();                                                                   \
    LOADB(brv_n, ((i) + 2) * 64, STRIDE);                                     \
    SBAR();                                                                   \
    COMPUTE(curbuf);                                                          \
    asm volatile("s_waitcnt vmcnt(8) lgkmcnt(0)" ::: "memory");               \
    __builtin_amdgcn_s_barrier(); }

// ---------------- GEMM1: hh[p][F] = gelu(xb[tok] @ w1[e] + b1[e]) ----------------
// BM=160, BN=128, BK=64, NK=16. 1D grid with XCD-cohort id mapping:
//   id = (j>>3)*128 + nt*8 + (j&7)  =>  all 16 nt-panels of job j land on
//   XCD (j&7) (dispatch round-robins blockIdx%8 across XCDs), so the 16
//   interleaved 512B column-slices of w1[e] merge into contiguous 8KB row
//   sweeps in ONE L2 -> single HBM fetch per line, sequential DRAM pages.
__global__ __launch_bounds__(256, 2) void gemm1_kernel(
    const unsigned short* __restrict__ xb, const float* __restrict__ w1,
    const float* __restrict__ b1, const int* __restrict__ cnt,
    const int* __restrict__ lists, const int* __restrict__ job_e,
    const int* __restrict__ job_mt, const int* __restrict__ njobs,
    unsigned short* __restrict__ hh)
{
    const int id = blockIdx.x;
    const int j  = (id >> 7) * 8 + (id & 7);   // job
    const int nt = (id >> 3) & 15;             // n-tile
    if (j >= njobs[0]) return;
    const int e = job_e[j], mt = job_mt[j];
    const int count = cnt[e];
    const int* list = lists + e * MAXT + mt * BM;
    const int mloc = min(BM, count - mt * BM);

    __shared__ __align__(16) unsigned short As[2][BM * 64];    // 40 KB
    __shared__ __align__(16) unsigned short Bs[2][128 * 64];   // 32 KB

    const int t = threadIdx.x, lane = t & 63, wave = t >> 6;
    const int lrow = lane & 15, lq = lane >> 4;
    const int wm = (wave & 1) * 80, wn = (wave >> 1) * 64;

    const int achk = (lane & 7) ^ (lane >> 3);
    const unsigned short* aGp[5];
#pragma unroll
    for (int q = 0; q < 5; ++q) {
        const int r = wave * 40 + q * 8 + (lane >> 3);
        aGp[q] = xb + (size_t)(list[min(r, mloc - 1)] >> 1) * DDIM + achk * 8;
    }

    const int n4 = (t & 31) * 4, kg = t >> 5;
    const float* bG = w1 + (size_t)e * DDIM * FDIM + nt * 128 + n4;

    floatx4 acc[5][4];
#pragma unroll
    for (int ii = 0; ii < 5; ++ii)
#pragma unroll
        for (int jn = 0; jn < 4; ++jn) acc[ii][jn] = (floatx4)0.f;

    floatx4 brvA[8], brvB[8];

    // ---- prologue: tile0 -> LDS[0]; B(1) -> brvA (stays in flight) ----
    STAGEA(0, 0);
    SBAR();
    LOADB(brvB, 0, FDIM);
    WRITEB(brvB, 0);
    SBAR();
    LOADB(brvA, 64, FDIM);
    asm volatile("s_waitcnt vmcnt(8) lgkmcnt(0)" ::: "memory");
    __builtin_amdgcn_s_barrier();

    // ---- steady: tiles 0..13 ----
#pragma unroll 1
    for (int it = 0; it < 7; ++it) {
        const int i = it * 2;
        STEADY(i, 0, brvA, brvB, FDIM);
        STEADY(i + 1, 1, brvB, brvA, FDIM);
    }
    // ---- i = 14: stage tile 15, compute tile 14 ----
    STAGEA(1, 15 * 64);
    WRITEB(brvA, 1);
    SBAR();
    COMPUTE(0);
    asm volatile("s_waitcnt vmcnt(0) lgkmcnt(0)" ::: "memory");
    __builtin_amdgcn_s_barrier();
    // ---- i = 15 ----
    COMPUTE(1);

    // epilogue: bias + exact gelu -> hh (bf16)
#pragma unroll
    for (int jn = 0; jn < 4; ++jn) {
        const int n = nt * 128 + wn + jn * 16 + lrow;
        const float bias = b1[e * FDIM + n];
#pragma unroll
        for (int ii = 0; ii < 5; ++ii) {
#pragma unroll
            for (int r = 0; r < 4; ++r) {
                const int m = wm + ii * 16 + lq * 4 + r;
                if (m < mloc) {
                    const int pp = list[m];
                    float v = acc[ii][jn][r] + bias;
                    v = 0.5f * v * (1.0f + erff(v * 0.70710678118654752f));
                    hh[(size_t)pp * FDIM + n] = f2bf1(v);
                }
            }
        }
    }
}

// ---------------- GEMM2: out_slot[tok][D] = wt[p] * (hh[p] @ w2[e] + b2[e]) ----------------
// BM=160, BN=128, BK=64, NK=32. Same cohort mapping (8 nt-panels per job on
// one XCD); direct stores, no atomics.
__global__ __launch_bounds__(256, 2) void gemm2_kernel(
    const unsigned short* __restrict__ hh, const float* __restrict__ w2,
    const float* __restrict__ b2, const int* __restrict__ cnt,
    const int* __restrict__ lists, const int* __restrict__ job_e,
    const int* __restrict__ job_mt, const int* __restrict__ njobs,
    const float* __restrict__ wt, float* __restrict__ out0, float* __restrict__ out1)
{
    const int id = blockIdx.x;
    const int j  = (id >> 6) * 8 + (id & 7);   // job
    const int nt = (id >> 3) & 7;              // n-tile
    if (j >= njobs[0]) return;
    const int e = job_e[j], mt = job_mt[j];
    const int count = cnt[e];
    const int* list = lists + e * MAXT + mt * BM;
    const int mloc = min(BM, count - mt * BM);

    __shared__ __align__(16) unsigned short As[2][BM * 64];    // 40 KB
    __shared__ __align__(16) unsigned short Bs[2][128 * 64];   // 32 KB

    const int t = threadIdx.x, lane = t & 63, wave = t >> 6;
    const int lrow = lane & 15, lq = lane >> 4;
    const int wm = (wave & 1) * 80, wn = (wave >> 1) * 64;

    const int achk = (lane & 7) ^ (lane >> 3);
    const unsigned short* aGp[5];
#pragma unroll
    for (int q = 0; q < 5; ++q) {
        const int r = wave * 40 + q * 8 + (lane >> 3);
        aGp[q] = hh + (size_t)list[min(r, mloc - 1)] * FDIM + achk * 8;
    }

    const int n4 = (t & 31) * 4, kg = t >> 5;
    const float* bG = w2 + (size_t)e * FDIM * DDIM + nt * 128 + n4;

    floatx4 acc[5][4];
#pragma unroll
    for (int ii = 0; ii < 5; ++ii)
#pragma unroll
        for (int jn = 0; jn < 4; ++jn) acc[ii][jn] = (floatx4)0.f;

    floatx4 brvA[8], brvB[8];

    // ---- prologue ----
    STAGEA(0, 0);
    SBAR();
    LOADB(brvB, 0, DDIM);
    WRITEB(brvB, 0);
    SBAR();
    LOADB(brvA, 64, DDIM);
    asm volatile("s_waitcnt vmcnt(8) lgkmcnt(0)" ::: "memory");
    __builtin_amdgcn_s_barrier();

    // ---- steady: tiles 0..29 ----
#pragma unroll 1
    for (int it = 0; it < 15; ++it) {
        const int i = it * 2;
        STEADY(i, 0, brvA, brvB, DDIM);
        STEADY(i + 1, 1, brvB, brvA, DDIM);
    }
    // ---- i = 30: stage tile 31, compute tile 30 ----
    STAGEA(1, 31 * 64);
    WRITEB(brvA, 1);
    SBAR();
    COMPUTE(0);
    asm volatile("s_waitcnt vmcnt(0) lgkmcnt(0)" ::: "memory");
    __builtin_amdgcn_s_barrier();
    // ---- i = 31 ----
    COMPUTE(1);

#pragma unroll
    for (int jn = 0; jn < 4; ++jn) {
        const int n = nt * 128 + wn + jn * 16 + lrow;
        const float bias = b2[e * DDIM + n];
#pragma unroll
        for (int ii = 0; ii < 5; ++ii) {
#pragma unroll
            for (int r = 0; r < 4; ++r) {
                const int m = wm + ii * 16 + lq * 4 + r;
                if (m < mloc) {
                    const int pp = list[m];
                    const int tok = pp >> 1;
                    const float v = (acc[ii][jn][r] + bias) * wt[pp];
                    float* dst = (pp & 1) ? out1 : out0;
                    dst[(size_t)tok * DDIM + n] = v;
                }
            }
        }
    }
}

// ---------------- finalize: out = clip(x + out0 + out1) ----------------
__global__ __launch_bounds__(256) void finalize_kernel(
    const float* __restrict__ x, const float* __restrict__ o1,
    float* __restrict__ out)   // out currently holds out0
{
    const size_t i = ((size_t)blockIdx.x * 256 + threadIdx.x) * 4;
    float4 xv = *(const float4*)(x + i);
    float4 a  = *(const float4*)(out + i);
    float4 b  = *(const float4*)(o1 + i);
    float4 r;
    r.x = fminf(fmaxf(xv.x + a.x + b.x, -100.f), 100.f);
    r.y = fminf(fmaxf(xv.y + a.y + b.y, -100.f), 100.f);
    r.z = fminf(fmaxf(xv.z + a.z + b.z, -100.f), 100.f);
    r.w = fminf(fmaxf(xv.w + a.w + b.w, -100.f), 100.f);
    *(float4*)(out + i) = r;
}

extern "C" void kernel_launch(void* const* d_in, const int* in_sizes, int n_in,
                              void* d_out, int out_size, void* d_ws, size_t ws_size,
                              hipStream_t stream) {
    const float* h  = (const float*)d_in[0];
    const float* gw = (const float*)d_in[1];
    const float* w1 = (const float*)d_in[2];
    const float* b1 = (const float*)d_in[3];
    const float* w2 = (const float*)d_in[4];
    const float* b2 = (const float*)d_in[5];
    float* out = (float*)d_out;

    // workspace layout (bytes)
    char* ws = (char*)d_ws;
    int*   cnt    = (int*)ws;                         // 256
    int*   lists  = (int*)(ws + 256);                 // 114688
    float* wt     = (float*)(ws + 114944);            // 16384 -> 131328
    int*   job_e  = (int*)(ws + 131328);              // 512
    int*   job_mt = (int*)(ws + 131840);              // 512
    int*   njobs  = (int*)(ws + 132352);              // 256 -> 132608
    unsigned short* xb = (unsigned short*)(ws + 262144);            // 4 MB
    float* o1     = (float*)(ws + 262144 + 4194304);                // 8 MB
    unsigned short* hhb = (unsigned short*)(ws + 262144 + 4194304 + 8388608); // 16 MB
    // total ~28.3 MB

    cvtx_kernel<<<NTOK * DDIM / (256 * 8), 256, 0, stream>>>(h, xb, cnt);
    gate_kernel<<<NTOK / 4, 256, 0, stream>>>(h, gw, cnt, lists, wt);
    jobs_kernel<<<1, 64, 0, stream>>>(cnt, job_e, job_mt, njobs);
    // 1D grids with XCD-cohort id mapping: ceil(MAXJOBS/8)=5 cohort groups.
    gemm1_kernel<<<5 * 128, 256, 0, stream>>>(xb, w1, b1, cnt, lists, job_e, job_mt, njobs, hhb);
    gemm2_kernel<<<5 * 64, 256, 0, stream>>>(hhb, w2, b2, cnt, lists, job_e, job_mt, njobs, wt, out, o1);
    finalize_kernel<<<NTOK * DDIM / (256 * 4), 256, 0, stream>>>(h, o1, out);
}